// Round 1
// baseline (413.184 us; speedup 1.0000x reference)
//
#include <hip/hip_runtime.h>
#include <hip/hip_bf16.h>
#include <stdint.h>

// Problem dims (fixed)
#define NB  4
#define NS  2048
#define ND  768
#define NHD 12
#define NDK 64
#define NBH (NB*NHD)   // 48

typedef short short8 __attribute__((ext_vector_type(8)));
typedef float f32x4  __attribute__((ext_vector_type(4)));

#define MFMA16(a,b,c) __builtin_amdgcn_mfma_f32_16x16x32_bf16(a,b,c,0,0,0)

__device__ __forceinline__ short f2b(float f){
  union { float f; uint32_t u; } v; v.f = f;
  uint32_t u = v.u + 0x7fffu + ((v.u >> 16) & 1u);  // RNE
  return (short)(u >> 16);
}

__device__ __forceinline__ void gload16(const void* g, void* lds){
  __builtin_amdgcn_global_load_lds(
      (const __attribute__((address_space(1))) uint32_t*)g,
      (__attribute__((address_space(3))) uint32_t*)lds, 16, 0, 0);
}

// ---------------- elementwise fp32 -> bf16 cast ----------------
__global__ __launch_bounds__(256) void cast_f2bf(const float* __restrict__ in,
                                                 short* __restrict__ out, int n8){
  int i = blockIdx.x * 256 + threadIdx.x;
  if (i < n8){
    const f32x4* p = (const f32x4*)(in + (size_t)i*8);
    f32x4 v0 = p[0], v1 = p[1];
    short8 r;
    r[0]=f2b(v0[0]); r[1]=f2b(v0[1]); r[2]=f2b(v0[2]); r[3]=f2b(v0[3]);
    r[4]=f2b(v1[0]); r[5]=f2b(v1[1]); r[6]=f2b(v1[2]); r[7]=f2b(v1[3]);
    *(short8*)(out + (size_t)i*8) = r;
  }
}

// ---------------- 128x128x(K=768) bf16 GEMM core (m97 structure) ----------------
// A: (M,768) row-major bf16. Bw: (N,768) row-major bf16 ("B^T input": Y = A @ Bw^T).
// LDS tiles XOR-swizzled: lds_byte(r,kb) = (r*128 + kb) ^ ((r&7)<<4); global source
// pre-swizzled so global_load_lds (linear dest) lands data swizzled (rule #21).
__device__ __forceinline__ void gemm128_core(const short* __restrict__ A,
                                             const short* __restrict__ Bw,
                                             int rowA0, int rowB0,
                                             short* As, short* Bs, f32x4 acc[4][4]){
  const int t = threadIdx.x;
  const int l  = t & 63;
  const int wm = ((t >> 7) & 1) * 64;
  const int wn = ((t >> 6) & 1) * 64;
  const int lr = l & 15, lg = l >> 4;
  #pragma unroll
  for (int mt=0; mt<4; ++mt)
    #pragma unroll
    for (int nt=0; nt<4; ++nt) acc[mt][nt] = (f32x4){0.f,0.f,0.f,0.f};

  for (int kt = 0; kt < 12; ++kt){
    #pragma unroll
    for (int c = 0; c < 4; ++c){
      int u  = c*256 + t;
      int m  = u >> 3;
      int kb = ((u & 7) << 4) ^ ((m & 7) << 4);   // inverse-swizzled source
      gload16((const char*)(A  + (size_t)(rowA0 + m)*768 + kt*64) + kb,
              (char*)As + ((c*256 + (t & 0xC0)) << 4));
      gload16((const char*)(Bw + (size_t)(rowB0 + m)*768 + kt*64) + kb,
              (char*)Bs + ((c*256 + (t & 0xC0)) << 4));
    }
    __syncthreads();
    short8 af[4][2], bf[4][2];
    #pragma unroll
    for (int mt=0; mt<4; ++mt)
      #pragma unroll
      for (int ks=0; ks<2; ++ks){
        int m  = wm + mt*16 + lr;
        int kb = (ks*32 + lg*8) * 2;
        af[mt][ks] = *(const short8*)((const char*)As + ((m*128 + kb) ^ ((m & 7) << 4)));
        int n  = wn + mt*16 + lr;
        bf[mt][ks] = *(const short8*)((const char*)Bs + ((n*128 + kb) ^ ((n & 7) << 4)));
      }
    #pragma unroll
    for (int mt=0; mt<4; ++mt)
      #pragma unroll
      for (int nt=0; nt<4; ++nt){
        acc[mt][nt] = MFMA16(af[mt][0], bf[nt][0], acc[mt][nt]);
        acc[mt][nt] = MFMA16(af[mt][1], bf[nt][1], acc[mt][nt]);
      }
    __syncthreads();
  }
}

// QKV fused: grid (64, 18); y -> {Wq,Wk,Wv} x 6 n-tiles. bf16 output.
__global__ __launch_bounds__(256) void gemm_qkv(const short* __restrict__ Xb,
    const short* __restrict__ Wqb, const short* __restrict__ Wkb, const short* __restrict__ Wvb,
    short* __restrict__ Q, short* __restrict__ K, short* __restrict__ V){
  __shared__ __align__(16) short As[128*64];
  __shared__ __align__(16) short Bs[128*64];
  const int wsel = blockIdx.y / 6;
  const int nb   = (blockIdx.y % 6) * 128;
  const short* W = (wsel==0) ? Wqb : ((wsel==1) ? Wkb : Wvb);
  short*       O = (wsel==0) ? Q   : ((wsel==1) ? K   : V);
  f32x4 acc[4][4];
  gemm128_core(Xb, W, blockIdx.x*128, nb, As, Bs, acc);
  const int t = threadIdx.x, l = t & 63;
  const int wm = ((t>>7)&1)*64, wn = ((t>>6)&1)*64;
  const int lr = l & 15, lg = l >> 4;
  #pragma unroll
  for (int mt=0; mt<4; ++mt)
    #pragma unroll
    for (int nt=0; nt<4; ++nt)
      #pragma unroll
      for (int r=0; r<4; ++r){
        int m = blockIdx.x*128 + wm + mt*16 + lg*4 + r;
        int n = nb + wn + nt*16 + lr;
        O[(size_t)m*768 + n] = f2b(acc[mt][nt][r]);
      }
}

// Final projection: grid (64, 6). fp32 output.
__global__ __launch_bounds__(256) void gemm_out(const short* __restrict__ Hb,
    const short* __restrict__ W0b, float* __restrict__ out){
  __shared__ __align__(16) short As[128*64];
  __shared__ __align__(16) short Bs[128*64];
  const int nb = blockIdx.y * 128;
  f32x4 acc[4][4];
  gemm128_core(Hb, W0b, blockIdx.x*128, nb, As, Bs, acc);
  const int t = threadIdx.x, l = t & 63;
  const int wm = ((t>>7)&1)*64, wn = ((t>>6)&1)*64;
  const int lr = l & 15, lg = l >> 4;
  #pragma unroll
  for (int mt=0; mt<4; ++mt)
    #pragma unroll
    for (int nt=0; nt<4; ++nt)
      #pragma unroll
      for (int r=0; r<4; ++r){
        int m = blockIdx.x*128 + wm + mt*16 + lg*4 + r;
        int n = nb + wn + nt*16 + lr;
        out[(size_t)m*768 + n] = acc[mt][nt][r];
      }
}

// V (b,s,h,dk) -> Vt (b,h,dk,s)  so PV B-fragments are contiguous along s(=k).
__global__ __launch_bounds__(256) void transpose_v(const short* __restrict__ V,
                                                   short* __restrict__ Vt){
  __shared__ short tile[64][66];
  const int sb = blockIdx.x * 64;
  const int bh = blockIdx.y;
  const int b = bh / NHD, h = bh % NHD;
  const int t = threadIdx.x;
  {
    int r = t >> 2, dkb = (t & 3) * 16;
    const short* src = V + ((size_t)(b*NS + sb + r)*NHD + h)*NDK + dkb;
    short8 v0 = *(const short8*)src;
    short8 v1 = *(const short8*)(src + 8);
    #pragma unroll
    for (int j=0;j<8;++j) tile[r][dkb+j]   = v0[j];
    #pragma unroll
    for (int j=0;j<8;++j) tile[r][dkb+8+j] = v1[j];
  }
  __syncthreads();
  {
    int dk = t >> 2, s4 = (t & 3) * 16;
    short8 o0, o1;
    #pragma unroll
    for (int j=0;j<8;++j) o0[j] = tile[s4+j][dk];
    #pragma unroll
    for (int j=0;j<8;++j) o1[j] = tile[s4+8+j][dk];
    short* dst = Vt + ((size_t)bh*NDK + dk)*NS + sb + s4;
    *(short8*)dst     = o0;
    *(short8*)(dst+8) = o1;
  }
}

// Pass A: colsum over the QUERY axis. Per block: one (b,h), 128 k-rows, loop all q.
// T = K @ Q^T (rows=k, cols=q); accumulate per-lane partial exp-sums over columns,
// one cross-lane reduce at the end. Writes invs[bh*S + k] = 1/colsum[k].
__global__ __launch_bounds__(256) void pass_a(const short* __restrict__ Q,
                                              const short* __restrict__ K,
                                              float* __restrict__ invs){
  const int kb = blockIdx.x * 128;
  const int bh = blockIdx.y;
  const int b = bh / NHD, h = bh % NHD;
  const int t = threadIdx.x, w = t >> 6, l = t & 63;
  const int lr = l & 15, lg = l >> 4;
  const short* Qb = Q + ((size_t)b*NS*NHD + h)*NDK;  // row stride 768
  const short* Kb = K + ((size_t)b*NS*NHD + h)*NDK;

  short8 a[2][2];
  #pragma unroll
  for (int rt=0; rt<2; ++rt)
    #pragma unroll
    for (int ks=0; ks<2; ++ks){
      int krow = kb + w*32 + rt*16 + lr;
      a[rt][ks] = *(const short8*)(Kb + (size_t)krow*768 + ks*32 + lg*8);
    }

  float psum[2][4];
  #pragma unroll
  for (int rt=0;rt<2;++rt) for (int r=0;r<4;++r) psum[rt][r] = 0.f;

  for (int qi = 0; qi < 16; ++qi){
    short8 bq[8][2];
    #pragma unroll
    for (int ct=0; ct<8; ++ct)
      #pragma unroll
      for (int ks=0; ks<2; ++ks){
        int q = qi*128 + ct*16 + lr;
        bq[ct][ks] = *(const short8*)(Qb + (size_t)q*768 + ks*32 + lg*8);
      }
    f32x4 accs[2][8];
    #pragma unroll
    for (int rt=0; rt<2; ++rt)
      #pragma unroll
      for (int ct=0; ct<8; ++ct){
        f32x4 acc = (f32x4){0.f,0.f,0.f,0.f};
        acc = MFMA16(a[rt][0], bq[ct][0], acc);
        acc = MFMA16(a[rt][1], bq[ct][1], acc);
        accs[rt][ct] = acc;
      }
    #pragma unroll
    for (int rt=0; rt<2; ++rt)
      #pragma unroll
      for (int ct=0; ct<8; ++ct)
        #pragma unroll
        for (int r=0; r<4; ++r)
          psum[rt][r] += __expf(accs[rt][ct][r] * 0.125f);
  }
  #pragma unroll
  for (int rt=0; rt<2; ++rt)
    #pragma unroll
    for (int r=0; r<4; ++r){
      float v = psum[rt][r];
      v += __shfl_xor(v, 1); v += __shfl_xor(v, 2);
      v += __shfl_xor(v, 4); v += __shfl_xor(v, 8);
      if (lr == 0){
        int krow = kb + w*32 + rt*16 + lg*4 + r;
        invs[(size_t)bh*NS + krow] = 1.0f / v;
      }
    }
}

// Pass C: per (b,h, q-tile 128): loop k-tiles; S=Q@K^T, E=exp(S/8)*inv[k] (bf16,
// per-wave LDS roundtrip to reach A-fragment layout), heads += E @ V.
__global__ __launch_bounds__(256) void pass_c(const short* __restrict__ Q,
                                              const short* __restrict__ K,
                                              const short* __restrict__ Vt,
                                              const float* __restrict__ invs,
                                              short* __restrict__ Hd){
  __shared__ __align__(16) short E[4][32][136];
  const int qb = blockIdx.x * 128;
  const int bh = blockIdx.y;
  const int b = bh / NHD, h = bh % NHD;
  const int t = threadIdx.x, w = t >> 6, l = t & 63;
  const int lr = l & 15, lg = l >> 4;
  const short* Qb = Q  + ((size_t)b*NS*NHD + h)*NDK;
  const short* Kb = K  + ((size_t)b*NS*NHD + h)*NDK;
  const short* Vb = Vt + (size_t)bh*NDK*NS;
  const float* inv = invs + (size_t)bh*NS;

  short8 aq[2][2];
  #pragma unroll
  for (int qt=0; qt<2; ++qt)
    #pragma unroll
    for (int ks=0; ks<2; ++ks){
      int q = qb + w*32 + qt*16 + lr;
      aq[qt][ks] = *(const short8*)(Qb + (size_t)q*768 + ks*32 + lg*8);
    }

  f32x4 acch[2][4];
  #pragma unroll
  for (int qt=0;qt<2;++qt) for (int nt=0;nt<4;++nt) acch[qt][nt] = (f32x4){0.f,0.f,0.f,0.f};

  for (int kt = 0; kt < 16; ++kt){
    short8 bk[8][2];
    #pragma unroll
    for (int ct=0; ct<8; ++ct)
      #pragma unroll
      for (int ks=0; ks<2; ++ks){
        int krow = kt*128 + ct*16 + lr;
        bk[ct][ks] = *(const short8*)(Kb + (size_t)krow*768 + ks*32 + lg*8);
      }
    float invc[8];
    #pragma unroll
    for (int ct=0; ct<8; ++ct) invc[ct] = inv[kt*128 + ct*16 + lr];

    f32x4 accs[2][8];
    #pragma unroll
    for (int qt=0; qt<2; ++qt)
      #pragma unroll
      for (int ct=0; ct<8; ++ct){
        f32x4 acc = (f32x4){0.f,0.f,0.f,0.f};
        acc = MFMA16(aq[qt][0], bk[ct][0], acc);
        acc = MFMA16(aq[qt][1], bk[ct][1], acc);
        accs[qt][ct] = acc;
      }
    // E = exp(S/8) * inv_colsum, bf16, into per-wave LDS (C-layout -> [q][k])
    #pragma unroll
    for (int qt=0; qt<2; ++qt)
      #pragma unroll
      for (int ct=0; ct<8; ++ct)
        #pragma unroll
        for (int r=0; r<4; ++r){
          float e = __expf(accs[qt][ct][r] * 0.125f) * invc[ct];
          E[w][qt*16 + lg*4 + r][ct*16 + lr] = f2b(e);
        }
    __syncthreads();
    // PV: heads += E(16x32 slices) @ V(32x16 slices)
    #pragma unroll
    for (int ks4=0; ks4<4; ++ks4){
      short8 ae[2];
      #pragma unroll
      for (int qt=0; qt<2; ++qt)
        ae[qt] = *(const short8*)&E[w][qt*16 + lr][ks4*32 + lg*8];
      #pragma unroll
      for (int nt=0; nt<4; ++nt){
        short8 bv = *(const short8*)(Vb + (size_t)(nt*16 + lr)*NS + kt*128 + ks4*32 + lg*8);
        acch[0][nt] = MFMA16(ae[0], bv, acch[0][nt]);
        acch[1][nt] = MFMA16(ae[1], bv, acch[1][nt]);
      }
    }
    __syncthreads();
  }
  #pragma unroll
  for (int qt=0; qt<2; ++qt)
    #pragma unroll
    for (int nt=0; nt<4; ++nt)
      #pragma unroll
      for (int r=0; r<4; ++r){
        int q  = qb + w*32 + qt*16 + lg*4 + r;
        int dk = nt*16 + lr;
        Hd[((size_t)bh*NS + q)*NDK + dk] = f2b(acch[qt][nt][r]);
      }
}

extern "C" void kernel_launch(void* const* d_in, const int* in_sizes, int n_in,
                              void* d_out, int out_size, void* d_ws, size_t ws_size,
                              hipStream_t stream){
  (void)in_sizes; (void)n_in; (void)out_size; (void)ws_size;
  const float* x  = (const float*)d_in[0];
  const float* Wq = (const float*)d_in[1];
  const float* Wk = (const float*)d_in[2];
  const float* Wv = (const float*)d_in[3];
  const float* W0 = (const float*)d_in[4];

  char* ws = (char*)d_ws;
  const size_t SZ_X = (size_t)NB*NS*ND*2;   // 12,582,912 B
  const size_t SZ_W = (size_t)ND*ND*2;      //  1,179,648 B
  short* Xb   = (short*)(ws);               // reused as Hd after QKV GEMM
  short* Wqb  = (short*)(ws + SZ_X);
  short* Wkb  = (short*)(ws + SZ_X + 1*SZ_W);
  short* Wvb  = (short*)(ws + SZ_X + 2*SZ_W);
  short* W0b  = (short*)(ws + SZ_X + 3*SZ_W);
  short* Q    = (short*)(ws + 1*SZ_X + 4*SZ_W);
  short* K    = (short*)(ws + 2*SZ_X + 4*SZ_W);
  short* V    = (short*)(ws + 3*SZ_X + 4*SZ_W);
  short* Vt   = (short*)(ws + 4*SZ_X + 4*SZ_W);
  float* invs = (float*)(ws + 5*SZ_X + 4*SZ_W);
  short* Hd   = Xb;
  float* out  = (float*)d_out;

  cast_f2bf<<<dim3(3072), dim3(256), 0, stream>>>(x,  Xb,  NB*NS*ND/8);
  cast_f2bf<<<dim3(288),  dim3(256), 0, stream>>>(Wq, Wqb, ND*ND/8);
  cast_f2bf<<<dim3(288),  dim3(256), 0, stream>>>(Wk, Wkb, ND*ND/8);
  cast_f2bf<<<dim3(288),  dim3(256), 0, stream>>>(Wv, Wvb, ND*ND/8);
  cast_f2bf<<<dim3(288),  dim3(256), 0, stream>>>(W0, W0b, ND*ND/8);

  gemm_qkv<<<dim3(64,18), dim3(256), 0, stream>>>(Xb, Wqb, Wkb, Wvb, Q, K, V);
  transpose_v<<<dim3(32,48), dim3(256), 0, stream>>>(V, Vt);
  pass_a<<<dim3(16,48), dim3(256), 0, stream>>>(Q, K, invs);
  pass_c<<<dim3(16,48), dim3(256), 0, stream>>>(Q, K, Vt, invs, Hd);
  gemm_out<<<dim3(64,6), dim3(256), 0, stream>>>(Hd, W0b, out);
}

// Round 2
// 361.784 us; speedup vs baseline: 1.1421x; 1.1421x over previous
//
#include <hip/hip_runtime.h>
#include <hip/hip_bf16.h>
#include <stdint.h>

// Problem dims (fixed)
#define NB  4
#define NS  2048
#define ND  768
#define NHD 12
#define NDK 64
#define NBH (NB*NHD)   // 48

typedef short short8 __attribute__((ext_vector_type(8)));
typedef float f32x4  __attribute__((ext_vector_type(4)));
typedef float f32x16 __attribute__((ext_vector_type(16)));
typedef unsigned int uint2v __attribute__((ext_vector_type(2)));

#define MFMA16(a,b,c) __builtin_amdgcn_mfma_f32_16x16x32_bf16(a,b,c,0,0,0)
#define MFMA32(a,b,c) __builtin_amdgcn_mfma_f32_32x32x16_bf16(a,b,c,0,0,0)

__device__ __forceinline__ short f2b(float f){
  union { float f; uint32_t u; } v; v.f = f;
  uint32_t u = v.u + 0x7fffu + ((v.u >> 16) & 1u);  // RNE
  return (short)(u >> 16);
}
__device__ __forceinline__ float b2f(short s){
  union { float f; uint32_t u; } v; v.u = ((uint32_t)(unsigned short)s) << 16; return v.f;
}
__device__ __forceinline__ uint32_t cvtpk(float lo, float hi){
  uint32_t r;
  asm("v_cvt_pk_bf16_f32 %0, %1, %2" : "=v"(r) : "v"(lo), "v"(hi));
  return r;
}
__device__ __forceinline__ short8 mk8(uint32_t a, uint32_t b, uint32_t c, uint32_t d){
  union { uint32_t u[4]; short8 v; } x;
  x.u[0]=a; x.u[1]=b; x.u[2]=c; x.u[3]=d; return x.v;
}

__device__ __forceinline__ void gload16(const void* g, void* lds){
  __builtin_amdgcn_global_load_lds(
      (const __attribute__((address_space(1))) uint32_t*)g,
      (__attribute__((address_space(3))) uint32_t*)lds, 16, 0, 0);
}

// ---------------- elementwise fp32 -> bf16 cast ----------------
__global__ __launch_bounds__(256) void cast_f2bf(const float* __restrict__ in,
                                                 short* __restrict__ out, int n8){
  int i = blockIdx.x * 256 + threadIdx.x;
  if (i < n8){
    const f32x4* p = (const f32x4*)(in + (size_t)i*8);
    f32x4 v0 = p[0], v1 = p[1];
    short8 r;
    r[0]=f2b(v0[0]); r[1]=f2b(v0[1]); r[2]=f2b(v0[2]); r[3]=f2b(v0[3]);
    r[4]=f2b(v1[0]); r[5]=f2b(v1[1]); r[6]=f2b(v1[2]); r[7]=f2b(v1[3]);
    *(short8*)(out + (size_t)i*8) = r;
  }
}

// ---------------- 128x128x(K=768) bf16 GEMM core (m97 structure) ----------------
__device__ __forceinline__ void gemm128_core(const short* __restrict__ A,
                                             const short* __restrict__ Bw,
                                             int rowA0, int rowB0,
                                             short* As, short* Bs, f32x4 acc[4][4]){
  const int t = threadIdx.x;
  const int l  = t & 63;
  const int wm = ((t >> 7) & 1) * 64;
  const int wn = ((t >> 6) & 1) * 64;
  const int lr = l & 15, lg = l >> 4;
  #pragma unroll
  for (int mt=0; mt<4; ++mt)
    #pragma unroll
    for (int nt=0; nt<4; ++nt) acc[mt][nt] = (f32x4){0.f,0.f,0.f,0.f};

  for (int kt = 0; kt < 12; ++kt){
    #pragma unroll
    for (int c = 0; c < 4; ++c){
      int u  = c*256 + t;
      int m  = u >> 3;
      int kb = ((u & 7) << 4) ^ ((m & 7) << 4);   // inverse-swizzled source
      gload16((const char*)(A  + (size_t)(rowA0 + m)*768 + kt*64) + kb,
              (char*)As + ((c*256 + (t & 0xC0)) << 4));
      gload16((const char*)(Bw + (size_t)(rowB0 + m)*768 + kt*64) + kb,
              (char*)Bs + ((c*256 + (t & 0xC0)) << 4));
    }
    __syncthreads();
    short8 af[4][2], bf[4][2];
    #pragma unroll
    for (int mt=0; mt<4; ++mt)
      #pragma unroll
      for (int ks=0; ks<2; ++ks){
        int m  = wm + mt*16 + lr;
        int kb = (ks*32 + lg*8) * 2;
        af[mt][ks] = *(const short8*)((const char*)As + ((m*128 + kb) ^ ((m & 7) << 4)));
        int n  = wn + mt*16 + lr;
        bf[mt][ks] = *(const short8*)((const char*)Bs + ((n*128 + kb) ^ ((n & 7) << 4)));
      }
    #pragma unroll
    for (int mt=0; mt<4; ++mt)
      #pragma unroll
      for (int nt=0; nt<4; ++nt){
        acc[mt][nt] = MFMA16(af[mt][0], bf[nt][0], acc[mt][nt]);
        acc[mt][nt] = MFMA16(af[mt][1], bf[nt][1], acc[mt][nt]);
      }
    __syncthreads();
  }
}

// QKV fused: grid (64, 18)
__global__ __launch_bounds__(256) void gemm_qkv(const short* __restrict__ Xb,
    const short* __restrict__ Wqb, const short* __restrict__ Wkb, const short* __restrict__ Wvb,
    short* __restrict__ Q, short* __restrict__ K, short* __restrict__ V){
  __shared__ __align__(16) short As[128*64];
  __shared__ __align__(16) short Bs[128*64];
  const int wsel = blockIdx.y / 6;
  const int nb   = (blockIdx.y % 6) * 128;
  const short* W = (wsel==0) ? Wqb : ((wsel==1) ? Wkb : Wvb);
  short*       O = (wsel==0) ? Q   : ((wsel==1) ? K   : V);
  f32x4 acc[4][4];
  gemm128_core(Xb, W, blockIdx.x*128, nb, As, Bs, acc);
  const int t = threadIdx.x, l = t & 63;
  const int wm = ((t>>7)&1)*64, wn = ((t>>6)&1)*64;
  const int lr = l & 15, lg = l >> 4;
  #pragma unroll
  for (int mt=0; mt<4; ++mt)
    #pragma unroll
    for (int nt=0; nt<4; ++nt)
      #pragma unroll
      for (int r=0; r<4; ++r){
        int m = blockIdx.x*128 + wm + mt*16 + lg*4 + r;
        int n = nb + wn + nt*16 + lr;
        O[(size_t)m*768 + n] = f2b(acc[mt][nt][r]);
      }
}

// Final projection: grid (64, 6). fp32 output.
__global__ __launch_bounds__(256) void gemm_out(const short* __restrict__ Hb,
    const short* __restrict__ W0b, float* __restrict__ out){
  __shared__ __align__(16) short As[128*64];
  __shared__ __align__(16) short Bs[128*64];
  const int nb = blockIdx.y * 128;
  f32x4 acc[4][4];
  gemm128_core(Hb, W0b, blockIdx.x*128, nb, As, Bs, acc);
  const int t = threadIdx.x, l = t & 63;
  const int wm = ((t>>7)&1)*64, wn = ((t>>6)&1)*64;
  const int lr = l & 15, lg = l >> 4;
  #pragma unroll
  for (int mt=0; mt<4; ++mt)
    #pragma unroll
    for (int nt=0; nt<4; ++nt)
      #pragma unroll
      for (int r=0; r<4; ++r){
        int m = blockIdx.x*128 + wm + mt*16 + lg*4 + r;
        int n = nb + wn + nt*16 + lr;
        out[(size_t)m*768 + n] = acc[mt][nt][r];
      }
}

// Pass A: colsum over the QUERY axis. S^T = K@Q^T per 32x32 tile; psum over q.
// grid (16, 48): block covers 128 kv rows (4 waves x 32), streams all 2048 q.
__global__ __launch_bounds__(256) void pass_a(const short* __restrict__ Q,
                                              const short* __restrict__ K,
                                              float* __restrict__ invs){
  const int t = threadIdx.x, w = t >> 6, l = t & 63;
  const int lq = l & 31, hf = l >> 5;
  const int kv0 = blockIdx.x * 128 + w * 32;
  const int bh = blockIdx.y;
  const int b = bh / NHD, h = bh % NHD;
  const short* Qb = Q + ((size_t)b*NS*NHD + h)*NDK;  // row stride 768
  const short* Kb = K + ((size_t)b*NS*NHD + h)*NDK;

  // hoisted K A-fragments: A[m=kv][k=dk], lane row = lq, dk chunk = s*16 + hf*8
  short8 kf[4];
  #pragma unroll
  for (int s=0; s<4; ++s)
    kf[s] = *(const short8*)(Kb + (size_t)(kv0 + lq)*768 + s*16 + hf*8);

  float psum[16];
  #pragma unroll
  for (int r=0; r<16; ++r) psum[r] = 0.f;

  for (int qt = 0; qt < 64; ++qt){
    short8 qf[4];
    #pragma unroll
    for (int s=0; s<4; ++s)
      qf[s] = *(const short8*)(Qb + (size_t)(qt*32 + lq)*768 + s*16 + hf*8);
    f32x16 c = {};
    #pragma unroll
    for (int s=0; s<4; ++s) c = MFMA32(kf[s], qf[s], c);
    #pragma unroll
    for (int r=0; r<16; ++r) psum[r] += __expf(c[r] * 0.125f);
  }
  // reduce across the 32 q-columns of each half (masks 1..16 stay in-half)
  #pragma unroll
  for (int r=0; r<16; ++r){
    float v = psum[r];
    v += __shfl_xor(v, 1); v += __shfl_xor(v, 2);
    v += __shfl_xor(v, 4); v += __shfl_xor(v, 8); v += __shfl_xor(v, 16);
    if (lq == 0){
      int kv = kv0 + (r&3) + 8*(r>>2) + 4*hf;
      invs[(size_t)bh*NS + kv] = 1.0f / v;
    }
  }
}

// V (b,s,h,dk) -> Vt' (b,h,dk,s) with the per-s inverse colsum folded in.
__global__ __launch_bounds__(256) void transpose_v(const short* __restrict__ V,
                                                   const float* __restrict__ invs,
                                                   short* __restrict__ Vt){
  __shared__ short tile[64][66];
  const int sb = blockIdx.x * 64;
  const int bh = blockIdx.y;
  const int b = bh / NHD, h = bh % NHD;
  const int t = threadIdx.x;
  {
    int r = t >> 2, dkb = (t & 3) * 16;
    float iv = invs[(size_t)bh*NS + sb + r];
    const short* src = V + ((size_t)(b*NS + sb + r)*NHD + h)*NDK + dkb;
    short8 v0 = *(const short8*)src;
    short8 v1 = *(const short8*)(src + 8);
    #pragma unroll
    for (int j=0;j<8;++j) tile[r][dkb+j]   = f2b(b2f(v0[j]) * iv);
    #pragma unroll
    for (int j=0;j<8;++j) tile[r][dkb+8+j] = f2b(b2f(v1[j]) * iv);
  }
  __syncthreads();
  {
    int dk = t >> 2, s4 = (t & 3) * 16;
    short8 o0, o1;
    #pragma unroll
    for (int j=0;j<8;++j) o0[j] = tile[s4+j][dk];
    #pragma unroll
    for (int j=0;j<8;++j) o1[j] = tile[s4+8+j][dk];
    short* dst = Vt + ((size_t)bh*NDK + dk)*NS + sb + s4;
    *(short8*)dst     = o0;
    *(short8*)(dst+8) = o1;
  }
}

// Pass C: fully in-register. Per wave: 32 q, loop 64 kv-tiles of 32.
// S^T = mfma32(K,Q) -> exp -> cvt_pk+permlane32_swap -> P A-frags -> PV mfma32.
// No LDS, no barriers. inv[kv] is pre-folded into Vt'.
__global__ __launch_bounds__(256) void pass_c(const short* __restrict__ Q,
                                              const short* __restrict__ K,
                                              const short* __restrict__ Vt,
                                              short* __restrict__ Hd){
  const int t = threadIdx.x, w = t >> 6, l = t & 63;
  const int lq = l & 31, hf = l >> 5;
  const int qb = blockIdx.x * 128 + w * 32;
  const int bh = blockIdx.y;
  const int b = bh / NHD, h = bh % NHD;
  const short* Qb = Q  + ((size_t)b*NS*NHD + h)*NDK;
  const short* Kb = K  + ((size_t)b*NS*NHD + h)*NDK;
  const short* Vb = Vt + (size_t)bh*NDK*NS;

  // hoisted Q B-fragments: B[k=dk][n=q], lane col = lq, dk chunk = s*16 + hf*8
  short8 qf[4];
  #pragma unroll
  for (int s=0; s<4; ++s)
    qf[s] = *(const short8*)(Qb + (size_t)(qb + lq)*768 + s*16 + hf*8);

  f32x16 acc0 = {}, acc1 = {};   // heads[q][dk] for dk halves 0..31 / 32..63

  for (int kt = 0; kt < 64; ++kt){
    // K A-fragments for this kv-tile
    const short* kp = Kb + (size_t)(kt*32 + lq)*768 + hf*8;
    f32x16 c = {};
    {
      short8 k0 = *(const short8*)(kp);
      short8 k1 = *(const short8*)(kp + 16);
      short8 k2 = *(const short8*)(kp + 32);
      short8 k3 = *(const short8*)(kp + 48);
      c = MFMA32(k0, qf[0], c);
      c = MFMA32(k1, qf[1], c);
      c = MFMA32(k2, qf[2], c);
      c = MFMA32(k3, qf[3], c);
    }
    // P = exp(S/8); pack into PV A-fragments in-register
    float p[16];
    #pragma unroll
    for (int r=0; r<16; ++r) p[r] = __expf(c[r] * 0.125f);

    short8 pa[2];
    #pragma unroll
    for (int b2=0; b2<2; ++b2){
      uint32_t x0 = cvtpk(p[8*b2+0], p[8*b2+1]);
      uint32_t x1 = cvtpk(p[8*b2+2], p[8*b2+3]);
      uint32_t y0 = cvtpk(p[8*b2+4], p[8*b2+5]);
      uint32_t y1 = cvtpk(p[8*b2+6], p[8*b2+7]);
      uint2v r02 = __builtin_amdgcn_permlane32_swap(x0, y0, false, false);
      uint2v r13 = __builtin_amdgcn_permlane32_swap(x1, y1, false, false);
      pa[b2] = mk8(r02.x, r13.x, r02.y, r13.y);
    }
    // PV: B[k=kv][n=dk] from Vt' rows (contiguous 16B along kv)
    const short* vp = Vb + (size_t)lq*NS + kt*32 + hf*8;
    short8 bv00 = *(const short8*)(vp);
    short8 bv10 = *(const short8*)(vp + 16);
    short8 bv01 = *(const short8*)(vp + (size_t)32*NS);
    short8 bv11 = *(const short8*)(vp + (size_t)32*NS + 16);
    acc0 = MFMA32(pa[0], bv00, acc0);
    acc0 = MFMA32(pa[1], bv10, acc0);
    acc1 = MFMA32(pa[0], bv01, acc1);
    acc1 = MFMA32(pa[1], bv11, acc1);
  }

  #pragma unroll
  for (int r=0; r<16; ++r){
    int q = qb + (r&3) + 8*(r>>2) + 4*hf;
    short* dst = Hd + ((size_t)bh*NS + q)*NDK;
    dst[lq]      = f2b(acc0[r]);
    dst[32 + lq] = f2b(acc1[r]);
  }
}

extern "C" void kernel_launch(void* const* d_in, const int* in_sizes, int n_in,
                              void* d_out, int out_size, void* d_ws, size_t ws_size,
                              hipStream_t stream){
  (void)in_sizes; (void)n_in; (void)out_size; (void)ws_size;
  const float* x  = (const float*)d_in[0];
  const float* Wq = (const float*)d_in[1];
  const float* Wk = (const float*)d_in[2];
  const float* Wv = (const float*)d_in[3];
  const float* W0 = (const float*)d_in[4];

  char* ws = (char*)d_ws;
  const size_t SZ_X = (size_t)NB*NS*ND*2;   // 12,582,912 B
  const size_t SZ_W = (size_t)ND*ND*2;      //  1,179,648 B
  short* Xb   = (short*)(ws);               // reused as Hd after QKV GEMM
  short* Wqb  = (short*)(ws + SZ_X);
  short* Wkb  = (short*)(ws + SZ_X + 1*SZ_W);
  short* Wvb  = (short*)(ws + SZ_X + 2*SZ_W);
  short* W0b  = (short*)(ws + SZ_X + 3*SZ_W);
  short* Q    = (short*)(ws + 1*SZ_X + 4*SZ_W);
  short* K    = (short*)(ws + 2*SZ_X + 4*SZ_W);
  short* V    = (short*)(ws + 3*SZ_X + 4*SZ_W);
  short* Vt   = (short*)(ws + 4*SZ_X + 4*SZ_W);
  float* invs = (float*)(ws + 5*SZ_X + 4*SZ_W);
  short* Hd   = Xb;
  float* out  = (float*)d_out;

  cast_f2bf<<<dim3(3072), dim3(256), 0, stream>>>(x,  Xb,  NB*NS*ND/8);
  cast_f2bf<<<dim3(288),  dim3(256), 0, stream>>>(Wq, Wqb, ND*ND/8);
  cast_f2bf<<<dim3(288),  dim3(256), 0, stream>>>(Wk, Wkb, ND*ND/8);
  cast_f2bf<<<dim3(288),  dim3(256), 0, stream>>>(Wv, Wvb, ND*ND/8);
  cast_f2bf<<<dim3(288),  dim3(256), 0, stream>>>(W0, W0b, ND*ND/8);

  gemm_qkv<<<dim3(64,18), dim3(256), 0, stream>>>(Xb, Wqb, Wkb, Wvb, Q, K, V);
  pass_a<<<dim3(16,48), dim3(256), 0, stream>>>(Q, K, invs);
  transpose_v<<<dim3(32,48), dim3(256), 0, stream>>>(V, invs, Vt);
  pass_c<<<dim3(16,48), dim3(256), 0, stream>>>(Q, K, Vt, Hd);
  gemm_out<<<dim3(64,6), dim3(256), 0, stream>>>(Hd, W0b, out);
}

// Round 3
// 244.137 us; speedup vs baseline: 1.6924x; 1.4819x over previous
//
#include <hip/hip_runtime.h>
#include <hip/hip_bf16.h>
#include <stdint.h>
#include <math.h>

// Problem dims (fixed)
#define NB  4
#define NS  2048
#define ND  768
#define NHD 12
#define NDK 64
#define NBH (NB*NHD)   // 48

// Q pre-scale: 1/sqrt(DK) * log2(e) so passes use raw exp2
#define QSCALE 0.180336879f

typedef short short8 __attribute__((ext_vector_type(8)));
typedef float f32x4  __attribute__((ext_vector_type(4)));
typedef float f32x16 __attribute__((ext_vector_type(16)));
typedef unsigned int uint2v __attribute__((ext_vector_type(2)));

#define MFMA16(a,b,c) __builtin_amdgcn_mfma_f32_16x16x32_bf16(a,b,c,0,0,0)
#define MFMA32(a,b,c) __builtin_amdgcn_mfma_f32_32x32x16_bf16(a,b,c,0,0,0)

__device__ __forceinline__ short f2b(float f){
  union { float f; uint32_t u; } v; v.f = f;
  uint32_t u = v.u + 0x7fffu + ((v.u >> 16) & 1u);  // RNE
  return (short)(u >> 16);
}
__device__ __forceinline__ float b2f(short s){
  union { float f; uint32_t u; } v; v.u = ((uint32_t)(unsigned short)s) << 16; return v.f;
}
__device__ __forceinline__ uint32_t cvtpk(float lo, float hi){
  uint32_t r;
  asm("v_cvt_pk_bf16_f32 %0, %1, %2" : "=v"(r) : "v"(lo), "v"(hi));
  return r;
}
__device__ __forceinline__ short8 mk8(uint32_t a, uint32_t b, uint32_t c, uint32_t d){
  union { uint32_t u[4]; short8 v; } x;
  x.u[0]=a; x.u[1]=b; x.u[2]=c; x.u[3]=d; return x.v;
}

__device__ __forceinline__ void gload16(const void* g, void* lds){
  __builtin_amdgcn_global_load_lds(
      (const __attribute__((address_space(1))) uint32_t*)g,
      (__attribute__((address_space(3))) uint32_t*)lds, 16, 0, 0);
}

// ---------------- elementwise fp32 -> bf16 cast ----------------
__global__ __launch_bounds__(256) void cast_f2bf(const float* __restrict__ in,
                                                 short* __restrict__ out, int n8){
  int i = blockIdx.x * 256 + threadIdx.x;
  if (i < n8){
    const f32x4* p = (const f32x4*)(in + (size_t)i*8);
    f32x4 v0 = p[0], v1 = p[1];
    short8 r;
    r[0]=f2b(v0[0]); r[1]=f2b(v0[1]); r[2]=f2b(v0[2]); r[3]=f2b(v0[3]);
    r[4]=f2b(v1[0]); r[5]=f2b(v1[1]); r[6]=f2b(v1[2]); r[7]=f2b(v1[3]);
    *(short8*)(out + (size_t)i*8) = r;
  }
}

// ---------------- 128x128x(K=768) bf16 GEMM core (m97 structure) ----------------
__device__ __forceinline__ void gemm128_core(const short* __restrict__ A,
                                             const short* __restrict__ Bw,
                                             int rowA0, int rowB0,
                                             short* As, short* Bs, f32x4 acc[4][4]){
  const int t = threadIdx.x;
  const int l  = t & 63;
  const int wm = ((t >> 7) & 1) * 64;
  const int wn = ((t >> 6) & 1) * 64;
  const int lr = l & 15, lg = l >> 4;
  #pragma unroll
  for (int mt=0; mt<4; ++mt)
    #pragma unroll
    for (int nt=0; nt<4; ++nt) acc[mt][nt] = (f32x4){0.f,0.f,0.f,0.f};

  for (int kt = 0; kt < 12; ++kt){
    #pragma unroll
    for (int c = 0; c < 4; ++c){
      int u  = c*256 + t;
      int m  = u >> 3;
      int kb = ((u & 7) << 4) ^ ((m & 7) << 4);   // inverse-swizzled source
      gload16((const char*)(A  + (size_t)(rowA0 + m)*768 + kt*64) + kb,
              (char*)As + ((c*256 + (t & 0xC0)) << 4));
      gload16((const char*)(Bw + (size_t)(rowB0 + m)*768 + kt*64) + kb,
              (char*)Bs + ((c*256 + (t & 0xC0)) << 4));
    }
    __syncthreads();
    short8 af[4][2], bf[4][2];
    #pragma unroll
    for (int mt=0; mt<4; ++mt)
      #pragma unroll
      for (int ks=0; ks<2; ++ks){
        int m  = wm + mt*16 + lr;
        int kb = (ks*32 + lg*8) * 2;
        af[mt][ks] = *(const short8*)((const char*)As + ((m*128 + kb) ^ ((m & 7) << 4)));
        int n  = wn + mt*16 + lr;
        bf[mt][ks] = *(const short8*)((const char*)Bs + ((n*128 + kb) ^ ((n & 7) << 4)));
      }
    #pragma unroll
    for (int mt=0; mt<4; ++mt)
      #pragma unroll
      for (int nt=0; nt<4; ++nt){
        acc[mt][nt] = MFMA16(af[mt][0], bf[nt][0], acc[mt][nt]);
        acc[mt][nt] = MFMA16(af[mt][1], bf[nt][1], acc[mt][nt]);
      }
    __syncthreads();
  }
}

// QKV fused: grid (64, 18). Q/K written in fragment-packed layout:
//   Xf[((bh*64 + (s>>5))*4 + (dk>>4))*512 + ((dk>>3)&1)*256 + (s&31)*8 + (dk&7)]
// Q pre-scaled by QSCALE. V written row-major (b,s,h,dk) for pack_v.
__global__ __launch_bounds__(256) void gemm_qkv(const short* __restrict__ Xb,
    const short* __restrict__ Wqb, const short* __restrict__ Wkb, const short* __restrict__ Wvb,
    short* __restrict__ Qf, short* __restrict__ Kf, short* __restrict__ V){
  __shared__ __align__(16) short As[128*64];
  __shared__ __align__(16) short Bs[128*64];
  const int wsel = blockIdx.y / 6;
  const int nb   = (blockIdx.y % 6) * 128;
  const short* W = (wsel==0) ? Wqb : ((wsel==1) ? Wkb : Wvb);
  f32x4 acc[4][4];
  gemm128_core(Xb, W, blockIdx.x*128, nb, As, Bs, acc);
  const int t = threadIdx.x, l = t & 63;
  const int wm = ((t>>7)&1)*64, wn = ((t>>6)&1)*64;
  const int lr = l & 15, lg = l >> 4;
  if (wsel == 2){
    #pragma unroll
    for (int mt=0; mt<4; ++mt)
      #pragma unroll
      for (int nt=0; nt<4; ++nt)
        #pragma unroll
        for (int r=0; r<4; ++r){
          int m = blockIdx.x*128 + wm + mt*16 + lg*4 + r;
          int n = nb + wn + nt*16 + lr;
          V[(size_t)m*768 + n] = f2b(acc[mt][nt][r]);
        }
  } else {
    short* O = (wsel==0) ? Qf : Kf;
    const float scl = (wsel==0) ? QSCALE : 1.0f;
    const int bh = (blockIdx.x >> 4)*NHD + ((nb + wn) >> 6);
    const int s0 = (blockIdx.x & 15)*128 + wm;
    short* Ob = O + (size_t)bh*131072;   // 64 kt * 2048
    #pragma unroll
    for (int mt=0; mt<4; ++mt)
      #pragma unroll
      for (int nt=0; nt<4; ++nt)
        #pragma unroll
        for (int r=0; r<4; ++r){
          int s  = s0 + mt*16 + lg*4 + r;
          int dk = nt*16 + lr;
          Ob[(size_t)((s>>5)*4 + (dk>>4))*512 + ((dk>>3)&1)*256 + (s&31)*8 + (dk&7)]
            = f2b(acc[mt][nt][r] * scl);
        }
  }
}

// Final projection: grid (64, 6). fp32 output.
__global__ __launch_bounds__(256) void gemm_out(const short* __restrict__ Hb,
    const short* __restrict__ W0b, float* __restrict__ out){
  __shared__ __align__(16) short As[128*64];
  __shared__ __align__(16) short Bs[128*64];
  const int nb = blockIdx.y * 128;
  f32x4 acc[4][4];
  gemm128_core(Hb, W0b, blockIdx.x*128, nb, As, Bs, acc);
  const int t = threadIdx.x, l = t & 63;
  const int wm = ((t>>7)&1)*64, wn = ((t>>6)&1)*64;
  const int lr = l & 15, lg = l >> 4;
  #pragma unroll
  for (int mt=0; mt<4; ++mt)
    #pragma unroll
    for (int nt=0; nt<4; ++nt)
      #pragma unroll
      for (int r=0; r<4; ++r){
        int m = blockIdx.x*128 + wm + mt*16 + lg*4 + r;
        int n = nb + wn + nt*16 + lr;
        out[(size_t)m*768 + n] = acc[mt][nt][r];
      }
}

// Pass A: colsum over the QUERY axis. grid (16,48), 4 waves x 32 kv each.
// All loads are packed-fragment granules: lane l reads granule[l] (coalesced).
__global__ __launch_bounds__(256) void pass_a(const short* __restrict__ Qf,
                                              const short* __restrict__ Kf,
                                              float* __restrict__ invs){
  const int t = threadIdx.x, w = t >> 6, l = t & 63;
  const int lq = l & 31, hf = l >> 5;
  const int bh = blockIdx.y;
  const int kt0 = blockIdx.x*4 + w;
  const short8* Kg = (const short8*)(Kf + ((size_t)bh*64 + kt0)*2048);
  short8 kf4[4];
  #pragma unroll
  for (int c=0; c<4; ++c) kf4[c] = Kg[c*64 + l];

  float psum[16];
  #pragma unroll
  for (int r=0; r<16; ++r) psum[r] = 0.f;

  const short8* Qb = (const short8*)(Qf + (size_t)bh*131072);
  for (int qt = 0; qt < 64; ++qt){
    const short8* Qg = Qb + qt*256;
    short8 q0 = Qg[l], q1 = Qg[64+l], q2 = Qg[128+l], q3 = Qg[192+l];
    f32x16 c = {};
    c = MFMA32(kf4[0], q0, c);
    c = MFMA32(kf4[1], q1, c);
    c = MFMA32(kf4[2], q2, c);
    c = MFMA32(kf4[3], q3, c);
    #pragma unroll
    for (int r=0; r<16; ++r) psum[r] += exp2f(c[r]);
  }
  #pragma unroll
  for (int r=0; r<16; ++r){
    float v = psum[r];
    v += __shfl_xor(v, 1); v += __shfl_xor(v, 2);
    v += __shfl_xor(v, 4); v += __shfl_xor(v, 8); v += __shfl_xor(v, 16);
    if (lq == 0){
      int kv = kt0*32 + (r&3) + 8*(r>>2) + 4*hf;
      invs[(size_t)bh*NS + kv] = 1.0f / v;
    }
  }
}

// V (b,s,h,dk) -> Vf fragment-packed with inverse colsum folded in.
// Vf granule (bh,kt,c): lane l = lq + hf*32 holds V[kv=kt*32+(c&1)*16+hf*8+e][dk=(c>>1)*32+lq]*inv[kv]
__global__ __launch_bounds__(256) void pack_v(const short* __restrict__ V,
                                              const float* __restrict__ invs,
                                              short* __restrict__ Vf){
  __shared__ short tile[64][66];
  const int sb = blockIdx.x * 64;
  const int bh = blockIdx.y;
  const int b = bh / NHD, h = bh % NHD;
  const int t = threadIdx.x;
  {
    int r = t >> 2, dkb = (t & 3) * 16;
    float iv = invs[(size_t)bh*NS + sb + r];
    const short* src = V + ((size_t)(b*NS + sb + r)*NHD + h)*NDK + dkb;
    short8 v0 = *(const short8*)src;
    short8 v1 = *(const short8*)(src + 8);
    #pragma unroll
    for (int j=0;j<8;++j) tile[r][dkb+j]   = f2b(b2f(v0[j]) * iv);
    #pragma unroll
    for (int j=0;j<8;++j) tile[r][dkb+8+j] = f2b(b2f(v1[j]) * iv);
  }
  __syncthreads();
  {
    const int c = t >> 6, l = t & 63;
    const int lq = l & 31, hf = l >> 5;
    const int dk = (c>>1)*32 + lq;
    #pragma unroll
    for (int kt_l = 0; kt_l < 2; ++kt_l){
      int kv0 = kt_l*32 + (c&1)*16 + hf*8;
      short8 o;
      #pragma unroll
      for (int j=0;j<8;++j) o[j] = tile[kv0+j][dk];
      *(short8*)(Vf + (((size_t)bh*64 + (sb>>5) + kt_l)*256 + c*64 + l)*8) = o;
    }
  }
}

// Pass C: fully in-register, fragment-packed streaming. grid (16,48),
// 4 waves x 32 q each; loop 64 kv-tiles. No LDS, no barriers.
__global__ __launch_bounds__(256) void pass_c(const short* __restrict__ Qf,
                                              const short* __restrict__ Kf,
                                              const short* __restrict__ Vf,
                                              short* __restrict__ Hd){
  const int t = threadIdx.x, w = t >> 6, l = t & 63;
  const int lq = l & 31, hf = l >> 5;
  const int bh = blockIdx.y;
  const int qt = blockIdx.x*4 + w;

  const short8* Qg = (const short8*)(Qf + ((size_t)bh*64 + qt)*2048);
  short8 qf4[4];
  #pragma unroll
  for (int c=0; c<4; ++c) qf4[c] = Qg[c*64 + l];

  const short8* Kb = (const short8*)(Kf + (size_t)bh*131072);
  const short8* Vb = (const short8*)(Vf + (size_t)bh*131072);

  f32x16 acc0 = {}, acc1 = {};   // heads[q][dk] halves

  for (int kt = 0; kt < 64; ++kt){
    const short8* Kg = Kb + kt*256;
    const short8* Vg = Vb + kt*256;
    short8 k0 = Kg[l], k1 = Kg[64+l], k2 = Kg[128+l], k3 = Kg[192+l];
    short8 v0 = Vg[l], v1 = Vg[64+l], v2 = Vg[128+l], v3 = Vg[192+l];

    f32x16 c = {};
    c = MFMA32(k0, qf4[0], c);
    c = MFMA32(k1, qf4[1], c);
    c = MFMA32(k2, qf4[2], c);
    c = MFMA32(k3, qf4[3], c);

    float p[16];
    #pragma unroll
    for (int r=0; r<16; ++r) p[r] = exp2f(c[r]);

    short8 pa[2];
    #pragma unroll
    for (int b2=0; b2<2; ++b2){
      uint32_t x0 = cvtpk(p[8*b2+0], p[8*b2+1]);
      uint32_t x1 = cvtpk(p[8*b2+2], p[8*b2+3]);
      uint32_t y0 = cvtpk(p[8*b2+4], p[8*b2+5]);
      uint32_t y1 = cvtpk(p[8*b2+6], p[8*b2+7]);
      uint2v r02 = __builtin_amdgcn_permlane32_swap(x0, y0, false, false);
      uint2v r13 = __builtin_amdgcn_permlane32_swap(x1, y1, false, false);
      pa[b2] = mk8(r02.x, r13.x, r02.y, r13.y);
    }
    acc0 = MFMA32(pa[0], v0, acc0);
    acc0 = MFMA32(pa[1], v1, acc0);
    acc1 = MFMA32(pa[0], v2, acc1);
    acc1 = MFMA32(pa[1], v3, acc1);
  }

  #pragma unroll
  for (int r=0; r<16; ++r){
    int q = qt*32 + (r&3) + 8*(r>>2) + 4*hf;
    short* dst = Hd + ((size_t)bh*NS + q)*NDK;
    dst[lq]      = f2b(acc0[r]);
    dst[32 + lq] = f2b(acc1[r]);
  }
}

extern "C" void kernel_launch(void* const* d_in, const int* in_sizes, int n_in,
                              void* d_out, int out_size, void* d_ws, size_t ws_size,
                              hipStream_t stream){
  (void)in_sizes; (void)n_in; (void)out_size; (void)ws_size;
  const float* x  = (const float*)d_in[0];
  const float* Wq = (const float*)d_in[1];
  const float* Wk = (const float*)d_in[2];
  const float* Wv = (const float*)d_in[3];
  const float* W0 = (const float*)d_in[4];

  char* ws = (char*)d_ws;
  const size_t SZ_X = (size_t)NB*NS*ND*2;   // 12,582,912 B
  const size_t SZ_W = (size_t)ND*ND*2;      //  1,179,648 B
  short* Xb   = (short*)(ws);               // reused as Hd after QKV GEMM
  short* Wqb  = (short*)(ws + SZ_X);
  short* Wkb  = (short*)(ws + SZ_X + 1*SZ_W);
  short* Wvb  = (short*)(ws + SZ_X + 2*SZ_W);
  short* W0b  = (short*)(ws + SZ_X + 3*SZ_W);
  short* Qf   = (short*)(ws + 1*SZ_X + 4*SZ_W);
  short* Kf   = (short*)(ws + 2*SZ_X + 4*SZ_W);
  short* V    = (short*)(ws + 3*SZ_X + 4*SZ_W);
  short* Vf   = (short*)(ws + 4*SZ_X + 4*SZ_W);
  float* invs = (float*)(ws + 5*SZ_X + 4*SZ_W);
  short* Hd   = Xb;
  float* out  = (float*)d_out;

  cast_f2bf<<<dim3(3072), dim3(256), 0, stream>>>(x,  Xb,  NB*NS*ND/8);
  cast_f2bf<<<dim3(288),  dim3(256), 0, stream>>>(Wq, Wqb, ND*ND/8);
  cast_f2bf<<<dim3(288),  dim3(256), 0, stream>>>(Wk, Wkb, ND*ND/8);
  cast_f2bf<<<dim3(288),  dim3(256), 0, stream>>>(Wv, Wvb, ND*ND/8);
  cast_f2bf<<<dim3(288),  dim3(256), 0, stream>>>(W0, W0b, ND*ND/8);

  gemm_qkv<<<dim3(64,18), dim3(256), 0, stream>>>(Xb, Wqb, Wkb, Wvb, Qf, Kf, V);
  pass_a<<<dim3(16,48), dim3(256), 0, stream>>>(Qf, Kf, invs);
  pack_v<<<dim3(32,48), dim3(256), 0, stream>>>(V, invs, Vf);
  pass_c<<<dim3(16,48), dim3(256), 0, stream>>>(Qf, Kf, Vf, Hd);
  gemm_out<<<dim3(64,6), dim3(256), 0, stream>>>(Hd, W0b, out);
}